// Round 1
// baseline (593.694 us; speedup 1.0000x reference)
//
#include <hip/hip_runtime.h>

#define C_IN    256
#define S_CELLS 90
#define A_OUT   2086
#define K_FC    180      // E * S = 2*90
#define B_BATCH 4096

// ---------------------------------------------------------------------------
// Kernel A: 1x1 conv + BN + 2-head attention (head_dim=1) + out_proj
//   -> flat [B, 180] (layout: flat[b][e*90 + s])
// One 128-thread sub-block per batch (block = 256 -> 2 batches).
// Thread s (<90) owns board cell s: computes y[e][s], its q0/q1, and the
// softmax-weighted sums over the 90 k/v values staged in LDS.
// ---------------------------------------------------------------------------
__global__ __launch_bounds__(256) void front_kernel(
    const float* __restrict__ x,        // [B,256,90]
    const float* __restrict__ conv_w,   // [2,256]
    const float* __restrict__ bn_gamma,
    const float* __restrict__ bn_beta,
    const float* __restrict__ bn_mean,
    const float* __restrict__ bn_var,
    const float* __restrict__ ipw,      // [6,2] rows: q0,q1,k0,k1,v0,v1
    const float* __restrict__ ipb,      // [6]
    const float* __restrict__ opw,      // [2,2]
    const float* __restrict__ opb,      // [2]
    float* __restrict__ flat)           // [B,180]
{
    __shared__ float4 kvpack[2][S_CELLS];   // (k0, v0, k1, v1) per cell

    const int half = threadIdx.x >> 7;       // which batch of this block
    const int s    = threadIdx.x & 127;      // cell index (active if < 90)
    const int b    = blockIdx.x * 2 + half;

    float q0 = 0.f, q1 = 0.f;

    if (s < S_CELLS) {
        // ---- 1x1 conv: y[e] = sum_c w[e][c] * x[b][c][s] ----
        // lane-contiguous in s -> coalesced; conv_w index is wave-uniform.
        const float* xb = x + (size_t)b * (C_IN * S_CELLS) + s;
        float a0 = 0.f, a1 = 0.f;
        #pragma unroll 8
        for (int c = 0; c < C_IN; ++c) {
            float xv = xb[(size_t)c * S_CELLS];
            a0 = fmaf(conv_w[c], xv, a0);
            a1 = fmaf(conv_w[C_IN + c], xv, a1);
        }
        // ---- BatchNorm (inference) ----
        const float sc0 = bn_gamma[0] * rsqrtf(bn_var[0] + 1e-5f);
        const float sc1 = bn_gamma[1] * rsqrtf(bn_var[1] + 1e-5f);
        const float y0 = a0 * sc0 + (bn_beta[0] - bn_mean[0] * sc0);
        const float y1 = a1 * sc1 + (bn_beta[1] - bn_mean[1] * sc1);
        // ---- packed QKV projection (E=2 -> 6) ----
        q0 = ipw[0] * y0 + ipw[1] * y1 + ipb[0];
        q1 = ipw[2] * y0 + ipw[3] * y1 + ipb[1];
        const float k0 = ipw[4] * y0 + ipw[5]  * y1 + ipb[2];
        const float k1 = ipw[6] * y0 + ipw[7]  * y1 + ipb[3];
        const float v0 = ipw[8] * y0 + ipw[9]  * y1 + ipb[4];
        const float v1 = ipw[10]* y0 + ipw[11] * y1 + ipb[5];
        kvpack[half][s] = make_float4(k0, v0, k1, v1);
    }
    __syncthreads();
    if (s < S_CELLS) {
        // ---- softmax(q_s * k_j) weighted sum of v (head_dim=1, scale=1) ----
        // exp range |q*k| <~ 10 -> safe in fp32 without max subtraction.
        float den0 = 0.f, num0 = 0.f, den1 = 0.f, num1 = 0.f;
        #pragma unroll 3
        for (int j = 0; j < S_CELLS; ++j) {
            const float4 kv = kvpack[half][j];   // LDS broadcast read
            const float e0 = __expf(q0 * kv.x);
            const float e1 = __expf(q1 * kv.z);
            den0 += e0; num0 = fmaf(e0, kv.y, num0);
            den1 += e1; num1 = fmaf(e1, kv.w, num1);
        }
        const float o0 = num0 / den0;
        const float o1 = num1 / den1;
        // ---- out_proj + transpose to [E,S] flat layout ----
        const float r0 = opw[0] * o0 + opw[1] * o1 + opb[0];
        const float r1 = opw[2] * o0 + opw[3] * o1 + opb[1];
        flat[(size_t)b * K_FC + s]           = r0;
        flat[(size_t)b * K_FC + S_CELLS + s] = r1;
    }
}

// ---------------------------------------------------------------------------
// Kernel B: out[b][a] = sum_j flat[b][j] * fc_w[a][j] + fc_b[a]
// M=4096, N=2086, K=180. Classic fp32 tiled GEMM: 64x64 block tile, BK=60,
// 256 threads, 4x4 micro-tile. Both operands are K-contiguous; tiles are
// transposed into [k][m]/[k][n] LDS (+4 pad: keeps 16B alignment for
// ds_read_b128 fragments and breaks store bank conflicts).
// ---------------------------------------------------------------------------
#define BM 64
#define BN 64
#define BK 60

__global__ __launch_bounds__(256) void fc_kernel(
    const float* __restrict__ Af,    // [4096,180]
    const float* __restrict__ W,     // [2086,180]
    const float* __restrict__ bias,  // [2086]
    float* __restrict__ out)         // [4096,2086]
{
    __shared__ float As[BK][BM + 4];
    __shared__ float Bs[BK][BN + 4];

    const int tid = threadIdx.x;
    const int tx  = tid & 15;    // n direction
    const int ty  = tid >> 4;    // m direction
    const int bm  = blockIdx.y * BM;
    const int bn  = blockIdx.x * BN;

    float acc[4][4] = {};

    for (int k0 = 0; k0 < K_FC; k0 += BK) {
        // stage A tile: 64 rows x 15 float4 (coalesced along K)
        for (int q = tid; q < BM * (BK / 4); q += 256) {
            const int m  = q / (BK / 4);
            const int kv = q % (BK / 4);
            const float4 v = *(const float4*)(Af + (size_t)(bm + m) * K_FC + k0 + kv * 4);
            const int kk = kv * 4;
            As[kk + 0][m] = v.x; As[kk + 1][m] = v.y;
            As[kk + 2][m] = v.z; As[kk + 3][m] = v.w;
        }
        // stage B tile (guard N tail with zero fill)
        for (int q = tid; q < BN * (BK / 4); q += 256) {
            const int n  = q / (BK / 4);
            const int kv = q % (BK / 4);
            const int gn = bn + n;
            float4 v = make_float4(0.f, 0.f, 0.f, 0.f);
            if (gn < A_OUT)
                v = *(const float4*)(W + (size_t)gn * K_FC + k0 + kv * 4);
            const int kk = kv * 4;
            Bs[kk + 0][n] = v.x; Bs[kk + 1][n] = v.y;
            Bs[kk + 2][n] = v.z; Bs[kk + 3][n] = v.w;
        }
        __syncthreads();

        #pragma unroll 6
        for (int k = 0; k < BK; ++k) {
            float a[4], bb[4];
            #pragma unroll
            for (int i = 0; i < 4; ++i) a[i] = As[k][ty * 4 + i];   // b128
            #pragma unroll
            for (int j = 0; j < 4; ++j) bb[j] = Bs[k][tx * 4 + j];  // b128
            #pragma unroll
            for (int i = 0; i < 4; ++i)
                #pragma unroll
                for (int j = 0; j < 4; ++j)
                    acc[i][j] = fmaf(a[i], bb[j], acc[i][j]);
        }
        __syncthreads();
    }

    // epilogue: bias + store (N=2086 rows are not 16B aligned -> scalar stores)
    #pragma unroll
    for (int i = 0; i < 4; ++i) {
        const int gm = bm + ty * 4 + i;
        #pragma unroll
        for (int j = 0; j < 4; ++j) {
            const int gn = bn + tx * 4 + j;
            if (gn < A_OUT)
                out[(size_t)gm * A_OUT + gn] = acc[i][j] + bias[gn];
        }
    }
}

// ---------------------------------------------------------------------------
extern "C" void kernel_launch(void* const* d_in, const int* in_sizes, int n_in,
                              void* d_out, int out_size, void* d_ws, size_t ws_size,
                              hipStream_t stream) {
    const float* x        = (const float*)d_in[0];
    const float* conv_w   = (const float*)d_in[1];
    const float* bn_gamma = (const float*)d_in[2];
    const float* bn_beta  = (const float*)d_in[3];
    const float* bn_mean  = (const float*)d_in[4];
    const float* bn_var   = (const float*)d_in[5];
    const float* ipw      = (const float*)d_in[6];
    const float* ipb      = (const float*)d_in[7];
    const float* opw      = (const float*)d_in[8];
    const float* opb      = (const float*)d_in[9];
    const float* fc_w     = (const float*)d_in[10];
    const float* fc_b     = (const float*)d_in[11];
    float* out  = (float*)d_out;
    float* flat = (float*)d_ws;   // [4096,180] fp32 = 2.95 MB scratch

    front_kernel<<<dim3(B_BATCH / 2), 256, 0, stream>>>(
        x, conv_w, bn_gamma, bn_beta, bn_mean, bn_var,
        ipw, ipb, opw, opb, flat);

    fc_kernel<<<dim3((A_OUT + BN - 1) / BN, B_BATCH / BM), 256, 0, stream>>>(
        flat, fc_w, fc_b, out);
}

// Round 2
// 593.686 us; speedup vs baseline: 1.0000x; 1.0000x over previous
//
#include <hip/hip_runtime.h>

#define C_IN    256
#define S_CELLS 90
#define A_OUT   2086
#define K_FC    180      // E * S = 2*90
#define B_BATCH 4096

// ---------------------------------------------------------------------------
// Kernel A: 1x1 conv + BN + 2-head attention (head_dim=1) + out_proj
//   -> flat [B, 180] (layout: flat[b][e*90 + s])
// 384-thread blocks; 4 batches per block (96-thread sub-blocks, 90 active:
// 94% lane utilization vs 70% for the 128-thread split). Thread s owns cell
// s: conv over 256 channels (coalesced channel-strided loads), QKV, then
// softmax-weighted v-sums over the 90 k/v float4s staged in LDS.
// ---------------------------------------------------------------------------
__global__ __launch_bounds__(384) void front_kernel(
    const float* __restrict__ x,        // [B,256,90]
    const float* __restrict__ conv_w,   // [2,256]
    const float* __restrict__ bn_gamma,
    const float* __restrict__ bn_beta,
    const float* __restrict__ bn_mean,
    const float* __restrict__ bn_var,
    const float* __restrict__ ipw,      // [6,2] rows: q0,q1,k0,k1,v0,v1
    const float* __restrict__ ipb,      // [6]
    const float* __restrict__ opw,      // [2,2]
    const float* __restrict__ opb,      // [2]
    float* __restrict__ flat)           // [B,180]
{
    __shared__ float4 kvpack[4][S_CELLS];   // (k0, v0, k1, v1) per cell

    const int sub = threadIdx.x / 96;        // which batch of this block
    const int s   = threadIdx.x % 96;        // cell index (active if < 90)
    const int b   = blockIdx.x * 4 + sub;

    float q0 = 0.f, q1 = 0.f;

    if (s < S_CELLS) {
        // ---- 1x1 conv: y[e] = sum_c w[e][c] * x[b][c][s] ----
        const float* xb = x + (size_t)b * (C_IN * S_CELLS) + s;
        float a0 = 0.f, a1 = 0.f;
        #pragma unroll 16
        for (int c = 0; c < C_IN; ++c) {
            float xv = xb[(size_t)c * S_CELLS];
            a0 = fmaf(conv_w[c], xv, a0);
            a1 = fmaf(conv_w[C_IN + c], xv, a1);
        }
        // ---- BatchNorm (inference) ----
        const float sc0 = bn_gamma[0] * rsqrtf(bn_var[0] + 1e-5f);
        const float sc1 = bn_gamma[1] * rsqrtf(bn_var[1] + 1e-5f);
        const float y0 = a0 * sc0 + (bn_beta[0] - bn_mean[0] * sc0);
        const float y1 = a1 * sc1 + (bn_beta[1] - bn_mean[1] * sc1);
        // ---- packed QKV projection (E=2 -> 6) ----
        q0 = ipw[0] * y0 + ipw[1] * y1 + ipb[0];
        q1 = ipw[2] * y0 + ipw[3] * y1 + ipb[1];
        const float k0 = ipw[4] * y0 + ipw[5]  * y1 + ipb[2];
        const float k1 = ipw[6] * y0 + ipw[7]  * y1 + ipb[3];
        const float v0 = ipw[8] * y0 + ipw[9]  * y1 + ipb[4];
        const float v1 = ipw[10]* y0 + ipw[11] * y1 + ipb[5];
        kvpack[sub][s] = make_float4(k0, v0, k1, v1);
    }
    __syncthreads();
    if (s < S_CELLS) {
        // ---- softmax(q_s * k_j) weighted sum of v (head_dim=1, scale=1) ----
        float den0 = 0.f, num0 = 0.f, den1 = 0.f, num1 = 0.f;
        #pragma unroll 5
        for (int j = 0; j < S_CELLS; ++j) {
            const float4 kv = kvpack[sub][j];   // LDS broadcast read
            const float e0 = __expf(q0 * kv.x);
            const float e1 = __expf(q1 * kv.z);
            den0 += e0; num0 = fmaf(e0, kv.y, num0);
            den1 += e1; num1 = fmaf(e1, kv.w, num1);
        }
        const float o0 = num0 / den0;
        const float o1 = num1 / den1;
        // ---- out_proj + transpose to [E,S] flat layout ----
        const float r0 = opw[0] * o0 + opw[1] * o1 + opb[0];
        const float r1 = opw[2] * o0 + opw[3] * o1 + opb[1];
        flat[(size_t)b * K_FC + s]           = r0;
        flat[(size_t)b * K_FC + S_CELLS + s] = r1;
    }
}

// ---------------------------------------------------------------------------
// Kernel B: out[b][a] = sum_j flat[b][j] * fc_w[a][j] + fc_b[a]
// M=4096, N=2086, K=180. fp32 tiled GEMM: 128x128 block tile, BK=36
// (=9 float4: K offsets 0,36,72,108,144 are all 16B-aligned in 180-float
// rows), 256 threads, 8x8 micro-tile. LDS 2x36x132x4 = 38 KB -> 4 blk/CU.
// 8x8 microtile halves LDS-cycles-per-FMA vs 4x4 (0.75 vs 1.5) -- the 64x64
// version was LDS-throughput-bound at ~3x its VALU floor.
// ---------------------------------------------------------------------------
#define BM 128
#define BN 128
#define BK 36
#define KV4 (BK / 4)   // 9 float4 per row-chunk

__global__ __launch_bounds__(256) void fc_kernel(
    const float* __restrict__ Af,    // [4096,180]
    const float* __restrict__ W,     // [2086,180]
    const float* __restrict__ bias,  // [2086]
    float* __restrict__ out)         // [4096,2086]
{
    __shared__ __align__(16) float As[BK][BM + 4];
    __shared__ __align__(16) float Bs[BK][BN + 4];

    const int tid = threadIdx.x;
    const int tx  = tid & 15;    // n direction (8 cols each)
    const int ty  = tid >> 4;    // m direction (8 rows each)
    const int bm  = blockIdx.y * BM;
    const int bn  = blockIdx.x * BN;

    float acc[8][8] = {};

    for (int k0 = 0; k0 < K_FC; k0 += BK) {
        // stage A tile: 128 rows x 9 float4, transposed into [k][m]
        for (int q = tid; q < BM * KV4; q += 256) {
            const int m  = q / KV4;
            const int kv = q % KV4;
            const float4 v = *(const float4*)(Af + (size_t)(bm + m) * K_FC + k0 + kv * 4);
            const int kk = kv * 4;
            As[kk + 0][m] = v.x; As[kk + 1][m] = v.y;
            As[kk + 2][m] = v.z; As[kk + 3][m] = v.w;
        }
        // stage B tile (zero-fill the N tail)
        for (int q = tid; q < BN * KV4; q += 256) {
            const int n  = q / KV4;
            const int kv = q % KV4;
            const int gn = bn + n;
            float4 v = make_float4(0.f, 0.f, 0.f, 0.f);
            if (gn < A_OUT)
                v = *(const float4*)(W + (size_t)gn * K_FC + k0 + kv * 4);
            const int kk = kv * 4;
            Bs[kk + 0][n] = v.x; Bs[kk + 1][n] = v.y;
            Bs[kk + 2][n] = v.z; Bs[kk + 3][n] = v.w;
        }
        __syncthreads();

        #pragma unroll 4
        for (int k = 0; k < BK; ++k) {
            float a[8], bb[8];
            // two b128 reads each; As reads broadcast (conflict-free),
            // Bs reads 4-way bank conflict (accepted; ~1.58x on half the LDS)
            const float4 a0 = *(const float4*)&As[k][ty * 8];
            const float4 a1 = *(const float4*)&As[k][ty * 8 + 4];
            const float4 b0 = *(const float4*)&Bs[k][tx * 8];
            const float4 b1 = *(const float4*)&Bs[k][tx * 8 + 4];
            a[0]=a0.x; a[1]=a0.y; a[2]=a0.z; a[3]=a0.w;
            a[4]=a1.x; a[5]=a1.y; a[6]=a1.z; a[7]=a1.w;
            bb[0]=b0.x; bb[1]=b0.y; bb[2]=b0.z; bb[3]=b0.w;
            bb[4]=b1.x; bb[5]=b1.y; bb[6]=b1.z; bb[7]=b1.w;
            #pragma unroll
            for (int i = 0; i < 8; ++i)
                #pragma unroll
                for (int j = 0; j < 8; ++j)
                    acc[i][j] = fmaf(a[i], bb[j], acc[i][j]);
        }
        __syncthreads();
    }

    // epilogue: bias + float2 stores (rows are 8-byte aligned: 2086*4 % 16 = 8,
    // so float4 would be misaligned; float2 pairs never straddle N=2086)
    #pragma unroll
    for (int i = 0; i < 8; ++i) {
        const int gm = bm + ty * 8 + i;
        #pragma unroll
        for (int p = 0; p < 4; ++p) {
            const int gn = bn + tx * 8 + p * 2;
            if (gn < A_OUT) {
                float2 v = make_float2(acc[i][p * 2]     + bias[gn],
                                       acc[i][p * 2 + 1] + bias[gn + 1]);
                *(float2*)(out + (size_t)gm * A_OUT + gn) = v;
            }
        }
    }
}

// ---------------------------------------------------------------------------
extern "C" void kernel_launch(void* const* d_in, const int* in_sizes, int n_in,
                              void* d_out, int out_size, void* d_ws, size_t ws_size,
                              hipStream_t stream) {
    const float* x        = (const float*)d_in[0];
    const float* conv_w   = (const float*)d_in[1];
    const float* bn_gamma = (const float*)d_in[2];
    const float* bn_beta  = (const float*)d_in[3];
    const float* bn_mean  = (const float*)d_in[4];
    const float* bn_var   = (const float*)d_in[5];
    const float* ipw      = (const float*)d_in[6];
    const float* ipb      = (const float*)d_in[7];
    const float* opw      = (const float*)d_in[8];
    const float* opb      = (const float*)d_in[9];
    const float* fc_w     = (const float*)d_in[10];
    const float* fc_b     = (const float*)d_in[11];
    float* out  = (float*)d_out;
    float* flat = (float*)d_ws;   // [4096,180] fp32 = 2.95 MB scratch

    front_kernel<<<dim3(B_BATCH / 4), 384, 0, stream>>>(
        x, conv_w, bn_gamma, bn_beta, bn_mean, bn_var,
        ipw, ipb, opw, opb, flat);

    fc_kernel<<<dim3((A_OUT + BN - 1) / BN, B_BATCH / BM), 256, 0, stream>>>(
        flat, fc_w, fc_b, out);
}

// Round 4
// 545.692 us; speedup vs baseline: 1.0880x; 1.0879x over previous
//
#include <hip/hip_runtime.h>

#define C_IN    256
#define S_CELLS 90
#define A_OUT   2086
#define K_FC    180      // E * S = 2*90
#define K_PAD   192      // K padded to 6*32 for mfma 16x16x32
#define N_PAD   2176     // 17 * 128
#define B_BATCH 4096

typedef __attribute__((ext_vector_type(8))) short short8;   // 8 bf16 = 4 VGPR
typedef __attribute__((ext_vector_type(4))) float floatx4;  // mfma C/D

static __device__ __forceinline__ unsigned short f2bf(float f) {
    // round-to-nearest-even fp32 -> bf16 (inputs are finite)
    unsigned u = __float_as_uint(f);
    return (unsigned short)((u + 0x7FFFu + ((u >> 16) & 1u)) >> 16);
}

// ---------------------------------------------------------------------------
// Kernel A: 1x1 conv + BN + 2-head attention (head_dim=1) + out_proj
//   -> Abf [B, 192] bf16 (j = e*90 + s; j in [180,192) zero pad)
// 384-thread blocks; 4 batches per block (96-thread sub-blocks, 90 active).
// ---------------------------------------------------------------------------
__global__ __launch_bounds__(384) void front_kernel(
    const float* __restrict__ x,        // [B,256,90]
    const float* __restrict__ conv_w,   // [2,256]
    const float* __restrict__ bn_gamma,
    const float* __restrict__ bn_beta,
    const float* __restrict__ bn_mean,
    const float* __restrict__ bn_var,
    const float* __restrict__ ipw,      // [6,2]
    const float* __restrict__ ipb,      // [6]
    const float* __restrict__ opw,      // [2,2]
    const float* __restrict__ opb,      // [2]
    unsigned short* __restrict__ Abf)   // [B,192] bf16
{
    __shared__ float4 kvpack[4][S_CELLS];   // (k0, v0, k1, v1) per cell

    const int sub = threadIdx.x / 96;
    const int s   = threadIdx.x % 96;
    const int b   = blockIdx.x * 4 + sub;

    float q0 = 0.f, q1 = 0.f;

    if (s < S_CELLS) {
        const float* xb = x + (size_t)b * (C_IN * S_CELLS) + s;
        float a0 = 0.f, a1 = 0.f;
        #pragma unroll 16
        for (int c = 0; c < C_IN; ++c) {
            float xv = xb[(size_t)c * S_CELLS];
            a0 = fmaf(conv_w[c], xv, a0);
            a1 = fmaf(conv_w[C_IN + c], xv, a1);
        }
        const float sc0 = bn_gamma[0] * rsqrtf(bn_var[0] + 1e-5f);
        const float sc1 = bn_gamma[1] * rsqrtf(bn_var[1] + 1e-5f);
        const float y0 = a0 * sc0 + (bn_beta[0] - bn_mean[0] * sc0);
        const float y1 = a1 * sc1 + (bn_beta[1] - bn_mean[1] * sc1);
        q0 = ipw[0] * y0 + ipw[1] * y1 + ipb[0];
        q1 = ipw[2] * y0 + ipw[3] * y1 + ipb[1];
        const float k0 = ipw[4] * y0 + ipw[5]  * y1 + ipb[2];
        const float k1 = ipw[6] * y0 + ipw[7]  * y1 + ipb[3];
        const float v0 = ipw[8] * y0 + ipw[9]  * y1 + ipb[4];
        const float v1 = ipw[10]* y0 + ipw[11] * y1 + ipb[5];
        kvpack[sub][s] = make_float4(k0, v0, k1, v1);
    }
    __syncthreads();
    if (s < S_CELLS) {
        float den0 = 0.f, num0 = 0.f, den1 = 0.f, num1 = 0.f;
        #pragma unroll 5
        for (int j = 0; j < S_CELLS; ++j) {
            const float4 kv = kvpack[sub][j];
            const float e0 = __expf(q0 * kv.x);
            const float e1 = __expf(q1 * kv.z);
            den0 += e0; num0 = fmaf(e0, kv.y, num0);
            den1 += e1; num1 = fmaf(e1, kv.w, num1);
        }
        const float o0 = num0 / den0;
        const float o1 = num1 / den1;
        const float r0 = opw[0] * o0 + opw[1] * o1 + opb[0];
        const float r1 = opw[2] * o0 + opw[3] * o1 + opb[1];
        Abf[(size_t)b * K_PAD + s]           = f2bf(r0);
        Abf[(size_t)b * K_PAD + S_CELLS + s] = f2bf(r1);
    } else {
        // threads s=90..95 zero the K pad (j = 180..191)
        Abf[(size_t)b * K_PAD + 180 + (s - S_CELLS)] = 0;
        Abf[(size_t)b * K_PAD + 186 + (s - S_CELLS)] = 0;
    }
}

// ---------------------------------------------------------------------------
// fc_w [2086,180] fp32 -> Wbf [2176,192] bf16, zero-padded rows & K tail.
// ---------------------------------------------------------------------------
__global__ __launch_bounds__(192) void wconv_kernel(
    const float* __restrict__ W, unsigned short* __restrict__ Wbf)
{
    const int n = blockIdx.x;        // 0..2175
    const int k = threadIdx.x;       // 0..191
    unsigned short v = 0;
    if (n < A_OUT && k < K_FC) v = f2bf(W[(size_t)n * K_FC + k]);
    Wbf[(size_t)n * K_PAD + k] = v;
}

// ---------------------------------------------------------------------------
// Kernel B: bf16 MFMA GEMM. out[m][n] = sum_k Abf[m][k]*Wbf[n][k] + bias[n]
// M=4096, N=2176(pad), K=192. Block 128x128, 256 thr = 4 waves in 2x2 of
// 64x64 wave-tiles; mfma_f32_16x16x32_bf16, BK=64 (2 k-steps/stage).
// LDS rows padded 64->72 bf16 (+16B): row stride 144 B = 36 banks -> frag
// reads land 2-way (free, m136) instead of 16-way.
// FIX (R3 NaN): each 64-bf16 row = 8 int4 chunks, not 4 — stage BM*8 chunks
// per operand (cols 32..63 were previously uninitialized LDS -> NaN).
// ---------------------------------------------------------------------------
#define BM 128
#define BN 128
#define BK 64
#define LDSROW 72

__global__ __launch_bounds__(256) void fc_mfma_kernel(
    const unsigned short* __restrict__ Abf,  // [4096,192] bf16
    const unsigned short* __restrict__ Wbf,  // [2176,192] bf16
    const float* __restrict__ bias,          // [2086]
    float* __restrict__ out)                 // [4096,2086] fp32
{
    __shared__ __align__(16) unsigned short As[BM * LDSROW];
    __shared__ __align__(16) unsigned short Bs[BN * LDSROW];

    const int tid  = threadIdx.x;
    const int lane = tid & 63;
    const int wave = tid >> 6;
    const int wy   = wave >> 1;          // M half (0/1)
    const int wx   = wave & 1;           // N half (0/1)
    const int lrow = lane & 15;
    const int lk   = (lane >> 4) * 8;    // k-offset within a 32-k step
    const int bm   = blockIdx.y * BM;
    const int bn   = blockIdx.x * BN;

    floatx4 acc[4][4] = {};

    for (int k0 = 0; k0 < K_PAD; k0 += BK) {
        // stage: 128 rows x 64 bf16 = 128 rows x 8 int4 chunks per operand,
        // 2048 chunks total / 256 threads = 8 per thread
        for (int q = tid; q < BM * 8; q += 256) {
            const int m = q >> 3, c = q & 7;
            *(int4*)&As[m * LDSROW + c * 8] =
                *(const int4*)(Abf + (size_t)(bm + m) * K_PAD + k0 + c * 8);
            *(int4*)&Bs[m * LDSROW + c * 8] =
                *(const int4*)(Wbf + (size_t)(bn + m) * K_PAD + k0 + c * 8);
        }
        __syncthreads();

        #pragma unroll
        for (int ks = 0; ks < 2; ++ks) {
            short8 af[4], bf[4];
            #pragma unroll
            for (int t = 0; t < 4; ++t) {
                af[t] = *(const short8*)&As[(wy * 64 + t * 16 + lrow) * LDSROW + ks * 32 + lk];
                bf[t] = *(const short8*)&Bs[(wx * 64 + t * 16 + lrow) * LDSROW + ks * 32 + lk];
            }
            #pragma unroll
            for (int mt = 0; mt < 4; ++mt)
                #pragma unroll
                for (int nt = 0; nt < 4; ++nt)
                    acc[mt][nt] = __builtin_amdgcn_mfma_f32_16x16x32_bf16(
                        af[mt], bf[nt], acc[mt][nt], 0, 0, 0);
        }
        __syncthreads();
    }

    // epilogue: C/D layout col=lane&15, row=(lane>>4)*4+r  [m89]
    const int ccol = lane & 15;
    const int crow = (lane >> 4) * 4;
    #pragma unroll
    for (int mt = 0; mt < 4; ++mt) {
        #pragma unroll
        for (int nt = 0; nt < 4; ++nt) {
            const int n_out = bn + wx * 64 + nt * 16 + ccol;
            if (n_out >= A_OUT) continue;
            const int m_base = bm + wy * 64 + mt * 16 + crow;
            const float bv = bias[n_out];
            #pragma unroll
            for (int r = 0; r < 4; ++r)
                out[(size_t)(m_base + r) * A_OUT + n_out] = acc[mt][nt][r] + bv;
        }
    }
}

// ---------------------------------------------------------------------------
extern "C" void kernel_launch(void* const* d_in, const int* in_sizes, int n_in,
                              void* d_out, int out_size, void* d_ws, size_t ws_size,
                              hipStream_t stream) {
    const float* x        = (const float*)d_in[0];
    const float* conv_w   = (const float*)d_in[1];
    const float* bn_gamma = (const float*)d_in[2];
    const float* bn_beta  = (const float*)d_in[3];
    const float* bn_mean  = (const float*)d_in[4];
    const float* bn_var   = (const float*)d_in[5];
    const float* ipw      = (const float*)d_in[6];
    const float* ipb      = (const float*)d_in[7];
    const float* opw      = (const float*)d_in[8];
    const float* opb      = (const float*)d_in[9];
    const float* fc_w     = (const float*)d_in[10];
    const float* fc_b     = (const float*)d_in[11];
    float* out = (float*)d_out;

    unsigned short* Abf = (unsigned short*)d_ws;                       // 4096*192*2 = 1.57 MB
    unsigned short* Wbf = (unsigned short*)((char*)d_ws + (size_t)B_BATCH * K_PAD * 2);

    front_kernel<<<dim3(B_BATCH / 4), 384, 0, stream>>>(
        x, conv_w, bn_gamma, bn_beta, bn_mean, bn_var,
        ipw, ipb, opw, opb, Abf);

    wconv_kernel<<<dim3(N_PAD), 192, 0, stream>>>(fc_w, Wbf);

    fc_mfma_kernel<<<dim3(N_PAD / BN, B_BATCH / BM), 256, 0, stream>>>(
        Abf, Wbf, fc_b, out);
}